// Round 5
// baseline (109.033 us; speedup 1.0000x reference)
//
#include <hip/hip_runtime.h>

// ScaledDotProductAttention w/ ALiBi + key padding mask. B=1,H=16,S=2048,D=64 fp32.
// R11: intra-block chunk parallelism — one block per (h,qblk), 8 waves =
// 4 q-strips x 2 KV-chunk groups. Each group walks half the live tile range
// with its own double-buffered K/V LDS (prefetch depth 1, 1 barrier/iter);
// the two groups' (O,l) partials merge in LDS. Deletes Opart/lp/Tickets and
// ALL cross-block coherent traffic (R6-R10 showed that exchange cost a
// conserved ~13us no matter where it ran).
// Carried: mask sniff, no online max (bias in acc init, exp2-domain), ALiBi
// window cut, pre-swizzled bf16 K/V^T, packed-u32 P round-trip, setprio.

constexpr int   S_LEN  = 2048;
constexpr int   D_DIM  = 64;
constexpr int   H_NUM  = 16;
constexpr int   QT     = 128;            // q rows per block (4 strips x 32)
constexpr int   K_TILE = 64;
constexpr int   NTILE  = S_LEN / K_TILE; // 32
constexpr int   QB     = S_LEN / QT;     // 16
constexpr int   PROWSTR= 36;             // dwords per P row (144B, 16B-mult)
constexpr float SCL    = 0.18033688f;    // 0.125 * log2(e)
constexpr float L2E    = 1.44269504f;
constexpr float MASKED = -50000.0f;      // exp2-domain masked-key sentinel -> exp2 = 0
constexpr float CUTOFF = 40.0f;          // log2-units: bias < -40 => key negligible

typedef short bf16x8 __attribute__((ext_vector_type(8)));
typedef short bf16x4 __attribute__((ext_vector_type(4)));
typedef float f32x4  __attribute__((ext_vector_type(4)));

__device__ inline short f2bf(float f) {
    union { float f; unsigned u; } x; x.f = f;
    return (short)((x.u + 0x7fffu + ((x.u >> 16) & 1u)) >> 16);  // RNE
}

__device__ inline unsigned pack2bf(float a, float b) {
#if __has_builtin(__builtin_amdgcn_cvt_pk_bf16_f32)
    auto p = __builtin_amdgcn_cvt_pk_bf16_f32(a, b);
    unsigned u; __builtin_memcpy(&u, &p, 4); return u;
#else
    return (unsigned)(unsigned short)f2bf(a) | ((unsigned)(unsigned short)f2bf(b) << 16);
#endif
}

__device__ inline float fexp2(float x) {
#if __has_builtin(__builtin_amdgcn_exp2f)
    return __builtin_amdgcn_exp2f(x);
#else
    return exp2f(x);
#endif
}

__device__ inline unsigned permb(unsigned hi, unsigned lo, unsigned sel) {
#if __has_builtin(__builtin_amdgcn_perm)
    return __builtin_amdgcn_perm(hi, lo, sel);
#else
    return (sel == 0x05040100u) ? ((lo & 0xffffu) | (hi << 16))
                                : ((lo >> 16) | (hi & 0xffff0000u));
#endif
}

__device__ inline void load_lds16(const void* g, void* l) {
    __builtin_amdgcn_global_load_lds((const __attribute__((address_space(1))) void*)g,
                                     (__attribute__((address_space(3))) void*)l, 16, 0, 0);
}

// first live tile for head h (identical IEEE expression in all kernels)
__device__ inline int head_t0(int h) {
    const float slope_l2e = exp2f(-0.5f * (float)(h + 1)) * L2E;
    const float kmin = 2047.0f - CUTOFF / slope_l2e;
    return kmin <= 0.0f ? 0 : ((int)kmin) >> 6;
}

// ---- preprocess: K -> bf16 row-chunk-swizzled, V -> bf16 transposed+swizzled,
//      bias (exp2 units, mask folded). Only live tiles. ----
__global__ __launch_bounds__(256)
void preprocess_kernel(const float* __restrict__ Km, const float* __restrict__ Vm,
                       const void* __restrict__ maskp,
                       short* __restrict__ Kswz, short* __restrict__ Vswz,
                       float* __restrict__ Bias)
{
    __shared__ int mask_is_i32;
    const int tid = threadIdx.x;
    const int kt = blockIdx.x, h = blockIdx.y;
    if (kt < head_t0(h)) return;            // dead tile for this head

    const int kbase = kt * K_TILE;
    const size_t tbase = ((size_t)h * S_LEN + kbase) * D_DIM;
    short* Kd = Kswz + ((size_t)h * NTILE + kt) * 4096;
    short* Vd = Vswz + ((size_t)h * NTILE + kt) * 4096;

    // parallel mask-dtype sniff: first wave, one load + ballot
    if (tid < 64) {
        const unsigned v = ((const unsigned*)maskp)[tid];
        const unsigned long long b = __ballot(v <= 1u);
        if (tid == 0) mask_is_i32 = (b == ~0ULL);
    }

    // K: chunk c of row `key` stored at c ^ (key&7)
    #pragma unroll
    for (int it = 0; it < 2; ++it) {
        const int idx = it * 256 + tid;
        const int key = idx >> 3, c = idx & 7;
        const float* src = Km + tbase + key * 64 + c * 8;
        float4 a = *(const float4*)src;
        float4 b = *(const float4*)(src + 4);
        unsigned u[4] = { pack2bf(a.x, a.y), pack2bf(a.z, a.w),
                          pack2bf(b.x, b.y), pack2bf(b.z, b.w) };
        bf16x8 kp; __builtin_memcpy(&kp, u, 16);
        *(bf16x8*)(Kd + key * 64 + ((c ^ (key & 7)) << 3)) = kp;
    }

    // V: 4x4 register transpose; row d, key-chunk (key>>3)^(d&7)
    {
        const int db = tid >> 4, kb = tid & 15;
        const int d4 = db * 4, key4 = kb * 4;
        float4 vv[4];
        #pragma unroll
        for (int j = 0; j < 4; ++j)
            vv[j] = *(const float4*)(Vm + tbase + (key4 + j) * 64 + d4);
        const float* vp = (const float*)vv;
        #pragma unroll
        for (int jj = 0; jj < 4; ++jj) {
            const int d = d4 + jj;
            bf16x4 ov;
            ov[0] = f2bf(vp[0 * 4 + jj]); ov[1] = f2bf(vp[1 * 4 + jj]);
            ov[2] = f2bf(vp[2 * 4 + jj]); ov[3] = f2bf(vp[3 * 4 + jj]);
            *(bf16x4*)(Vd + d * 64 + (((key4 >> 3) ^ (d & 7)) << 3) + (key4 & 7)) = ov;
        }
    }
    __syncthreads();
    if (tid < K_TILE) {
        const int key = kbase + tid;
        const int mv = mask_is_i32 ? ((const int*)maskp)[key]
                                   : (int)((const unsigned char*)maskp)[key];
        const float slope_l2e = exp2f(-0.5f * (float)(h + 1)) * L2E;
        Bias[h * S_LEN + key] = mv ? slope_l2e * (float)(key - (S_LEN - 1)) : MASKED;
    }
}

// ---- main flash kernel: 8 waves = 4 q-strips x 2 KV-chunk groups; per-group
//      double-buffered K/V staging (depth-1 prefetch, 1 barrier/iter);
//      LDS merge of the two groups' (O,l); direct normalized O write. ----
__global__ __launch_bounds__(512, 2)
void attn_main(const float* __restrict__ Qm, const short* __restrict__ Kswz,
               const short* __restrict__ Vswz, const float* __restrict__ Bias,
               float* __restrict__ Om)
{
    __shared__ short    k_lds[2][2][4096];   // [cw][buf][64x64 bf16] 32 KB
    __shared__ short    v_lds[2][2][4096];   // 32 KB
    __shared__ float    bias_lds[S_LEN / QB * QB / 1];  // placeholder sizing below
    __shared__ unsigned p_lds[8][32 * PROWSTR];         // 36.9 KB; reused as cb
    __shared__ float    l_cb[4][32];                    // 512 B

    // NOTE: bias_lds must hold the whole head's bias row (2048 floats = 8 KB).
    // (sized via the constant to keep the compiler honest)
    static_assert(sizeof(bias_lds) == S_LEN * sizeof(float), "bias_lds size");

    const int tid = threadIdx.x;
    const int wave = tid >> 6, lane = tid & 63;
    const int l16 = lane & 15, quad = lane >> 4;
    const int sw = wave & 3;                 // q-strip (32 rows)
    const int cw = wave >> 2;                // KV-chunk group
    const int h = blockIdx.y, qblk = blockIdx.x;

    const int t0 = head_t0(h);
    const int nt = NTILE - t0;
    const int nhalf = (nt + 1) >> 1;
    const int mylen  = (cw == 0) ? nhalf : nt - nhalf;     // group-uniform
    const int mybase = (cw == 0) ? t0 : t0 + nhalf;

    const unsigned psel = (quad < 2) ? 0x05040100u : 0x07060302u;
    const short* Kh = Kswz + (size_t)h * NTILE * 4096;
    const short* Vh = Vswz + (size_t)h * NTILE * 4096;
    unsigned* pw = p_lds[wave];
    const int swz = l16 & 7;
    const int so  = sw * 2048 + lane * 16;   // per-lane src byte offset in tile

    // ---- prologue: whole-head bias, first tile stage, Q frags ----
    *(float4*)&bias_lds[tid * 4] = *(const float4*)(Bias + (size_t)h * S_LEN + tid * 4);
    if (mylen > 0) {
        const char* kg = (const char*)(Kh + (size_t)mybase * 4096);
        const char* vg = (const char*)(Vh + (size_t)mybase * 4096);
        char* kl = (char*)&k_lds[cw][0][0] + sw * 2048;
        char* vl = (char*)&v_lds[cw][0][0] + sw * 2048;
        load_lds16(kg + so,        kl);
        load_lds16(kg + so + 1024, kl + 1024);
        load_lds16(vg + so,        vl);
        load_lds16(vg + so + 1024, vl + 1024);
    }

    // Q A-frags for 2 strips of this wave's 32 rows, scaled by 0.125*log2(e)
    bf16x8 qfrag[2][2];
    {
        const float* Qh = Qm + (size_t)h * S_LEN * D_DIM;
        #pragma unroll
        for (int s = 0; s < 2; ++s) {
            const int qrow = qblk * QT + sw * 32 + s * 16 + l16;
            #pragma unroll
            for (int t = 0; t < 2; ++t) {
                const float* src = Qh + (size_t)qrow * D_DIM + t * 32 + quad * 8;
                float4 a = *(const float4*)src;
                float4 b = *(const float4*)(src + 4);
                unsigned* qp = (unsigned*)&qfrag[s][t];
                qp[0] = pack2bf(a.x * SCL, a.y * SCL);
                qp[1] = pack2bf(a.z * SCL, a.w * SCL);
                qp[2] = pack2bf(b.x * SCL, b.y * SCL);
                qp[3] = pack2bf(b.z * SCL, b.w * SCL);
            }
        }
    }

    bf16x8 onesv;
    #pragma unroll
    for (int i = 0; i < 8; ++i) onesv[i] = (short)0x3F80;  // bf16 1.0

    f32x4 o_frag[2][4], l4[2];
    #pragma unroll
    for (int s = 0; s < 2; ++s) {
        #pragma unroll
        for (int cc = 0; cc < 4; ++cc) o_frag[s][cc] = (f32x4){0.f, 0.f, 0.f, 0.f};
        l4[s] = (f32x4){0.f, 0.f, 0.f, 0.f};
    }

    __syncthreads();   // first tiles staged (vmcnt drained), bias visible

    // ---- main loop: both chunk groups in lockstep; depth-1 prefetch ----
    for (int i = 0; i < nhalf; ++i) {
        const int buf = i & 1;
        if (i + 1 < mylen) {
            // prefetch next tile into the other buffer (read next iter)
            const int ktn = mybase + i + 1;
            const char* kg = (const char*)(Kh + (size_t)ktn * 4096);
            const char* vg = (const char*)(Vh + (size_t)ktn * 4096);
            char* kl = (char*)&k_lds[cw][buf ^ 1][0] + sw * 2048;
            char* vl = (char*)&v_lds[cw][buf ^ 1][0] + sw * 2048;
            load_lds16(kg + so,        kl);
            load_lds16(kg + so + 1024, kl + 1024);
            load_lds16(vg + so,        vl);
            load_lds16(vg + so + 1024, vl + 1024);
        }
        if (i < mylen) {
            const int kt = mybase + i;
            const float* bm = &bias_lds[kt * K_TILE];
            const short* kb = &k_lds[cw][buf][0];
            const short* vb = &v_lds[cw][buf][0];

            // S(+bias) = bias_init + Q K^T
            f32x4 sv[2][4];
            __builtin_amdgcn_s_setprio(1);
            #pragma unroll
            for (int cc = 0; cc < 4; ++cc) {
                const float b = bm[cc * 16 + l16];
                const f32x4 binit = (f32x4){b, b, b, b};
                sv[0][cc] = binit;
                sv[1][cc] = binit;
                #pragma unroll
                for (int t = 0; t < 2; ++t) {
                    bf16x8 bfrag = *(const bf16x8*)&kb[(cc * 16 + l16) * 64 + (((t * 4 + quad) ^ swz) << 3)];
                    sv[0][cc] = __builtin_amdgcn_mfma_f32_16x16x32_bf16(qfrag[0][t], bfrag, sv[0][cc], 0, 0, 0);
                    sv[1][cc] = __builtin_amdgcn_mfma_f32_16x16x32_bf16(qfrag[1][t], bfrag, sv[1][cc], 0, 0, 0);
                }
            }
            __builtin_amdgcn_s_setprio(0);

            // p = exp2(s) -> packed bf16 pairs in per-wave LDS rows
            #pragma unroll
            for (int s = 0; s < 2; ++s) {
                #pragma unroll
                for (int r = 0; r < 4; ++r) {
                    const float p0 = fexp2(sv[s][0][r]);
                    const float p1 = fexp2(sv[s][1][r]);
                    const float p2 = fexp2(sv[s][2][r]);
                    const float p3 = fexp2(sv[s][3][r]);
                    unsigned* pp = &pw[(s * 16 + quad * 4 + r) * PROWSTR + l16];
                    pp[0]  = pack2bf(p0, p1);
                    pp[16] = pack2bf(p2, p3);
                }
            }

            // O += P V ; l += P * ones
            #pragma unroll
            for (int t2 = 0; t2 < 2; ++t2) {
                bf16x8 pfrag[2];
                #pragma unroll
                for (int s = 0; s < 2; ++s) {
                    const unsigned* pr = &pw[(s * 16 + l16) * PROWSTR + t2 * 16 + (quad & 1) * 8];
                    uint4 w0 = *(const uint4*)(pr);
                    uint4 w1 = *(const uint4*)(pr + 4);
                    unsigned pf[4];
                    pf[0] = permb(w0.y, w0.x, psel);
                    pf[1] = permb(w0.w, w0.z, psel);
                    pf[2] = permb(w1.y, w1.x, psel);
                    pf[3] = permb(w1.w, w1.z, psel);
                    __builtin_memcpy(&pfrag[s], pf, 16);
                }
                __builtin_amdgcn_s_setprio(1);
                #pragma unroll
                for (int c2 = 0; c2 < 4; ++c2) {
                    bf16x8 vfrag = *(const bf16x8*)&vb[(c2 * 16 + l16) * 64 + (((t2 * 4 + quad) ^ swz) << 3)];
                    o_frag[0][c2] = __builtin_amdgcn_mfma_f32_16x16x32_bf16(pfrag[0], vfrag, o_frag[0][c2], 0, 0, 0);
                    o_frag[1][c2] = __builtin_amdgcn_mfma_f32_16x16x32_bf16(pfrag[1], vfrag, o_frag[1][c2], 0, 0, 0);
                }
                l4[0] = __builtin_amdgcn_mfma_f32_16x16x32_bf16(pfrag[0], onesv, l4[0], 0, 0, 0);
                l4[1] = __builtin_amdgcn_mfma_f32_16x16x32_bf16(pfrag[1], onesv, l4[1], 0, 0, 0);
                __builtin_amdgcn_s_setprio(0);
            }
        }
        __syncthreads();   // compute(buf) done everywhere; prefetch landed
    }

    // ---- LDS merge of the two chunk groups, then direct normalized write ----
    float* cb = (float*)p_lds;               // [4][32][68] floats (34.8 KB)
    if (cw == 1) {
        #pragma unroll
        for (int s = 0; s < 2; ++s) {
            #pragma unroll
            for (int c2 = 0; c2 < 4; ++c2) {
                #pragma unroll
                for (int r = 0; r < 4; ++r)
                    cb[(sw * 32 + s * 16 + quad * 4 + r) * 68 + c2 * 16 + l16] = o_frag[s][c2][r];
            }
            if (l16 == 0) {
                #pragma unroll
                for (int r = 0; r < 4; ++r)
                    l_cb[sw][s * 16 + quad * 4 + r] = l4[s][r];
            }
        }
    }
    __syncthreads();
    if (cw == 0) {
        float* Oh = Om + (size_t)h * S_LEN * D_DIM;
        const int qrow0 = qblk * QT + sw * 32;
        #pragma unroll
        for (int s = 0; s < 2; ++s) {
            #pragma unroll
            for (int r = 0; r < 4; ++r) {
                const int rrow = s * 16 + quad * 4 + r;
                float lsum = l4[s][r] + l_cb[sw][rrow];
                const float inv = 1.0f / lsum;
                const int row = qrow0 + rrow;
                float* dst = Oh + (size_t)row * D_DIM + l16;
                const float* cr = &cb[(sw * 32 + rrow) * 68];
                dst[0]  = (o_frag[s][0][r] + cr[0  + l16]) * inv;
                dst[16] = (o_frag[s][1][r] + cr[16 + l16]) * inv;
                dst[32] = (o_frag[s][2][r] + cr[32 + l16]) * inv;
                dst[48] = (o_frag[s][3][r] + cr[48 + l16]) * inv;
            }
        }
    }
}

extern "C" void kernel_launch(void* const* d_in, const int* in_sizes, int n_in,
                              void* d_out, int out_size, void* d_ws, size_t ws_size,
                              hipStream_t stream) {
    (void)in_sizes; (void)n_in; (void)out_size; (void)ws_size;
    const float* Q = (const float*)d_in[0];
    const float* K = (const float*)d_in[1];
    const float* V = (const float*)d_in[2];
    const void*  M = d_in[3];
    float* O = (float*)d_out;

    char* ws = (char*)d_ws;
    size_t off = 0;
    short* Kswz = (short*)(ws + off); off += (size_t)H_NUM * S_LEN * D_DIM * 2;   // 4 MB
    short* Vswz = (short*)(ws + off); off += (size_t)H_NUM * S_LEN * D_DIM * 2;   // 4 MB
    float* Bias = (float*)(ws + off); off += (size_t)H_NUM * S_LEN * 4;           // 128 KB

    preprocess_kernel<<<dim3(NTILE, H_NUM), 256, 0, stream>>>(K, V, M, Kswz, Vswz, Bias);
    attn_main<<<dim3(QB, H_NUM), 512, 0, stream>>>(Q, Kswz, Vswz, Bias, O);
}